// Round 16
// baseline (357.287 us; speedup 1.0000x reference)
//
#include <hip/hip_runtime.h>
#include <stdint.h>

typedef unsigned short u16;
typedef __bf16 bf16_t;
typedef bf16_t bf16x8 __attribute__((ext_vector_type(8)));
typedef float f32x4 __attribute__((ext_vector_type(4)));

__device__ __forceinline__ float b2f(u16 u) {
  union { unsigned int i; float f; } v; v.i = ((unsigned int)u) << 16; return v.f;
}
__device__ __forceinline__ u16 f2b(float f) {
  union { float f; unsigned int i; } v; v.f = f;
  unsigned int r = v.i + 0x7fffu + ((v.i >> 16) & 1u);  // RNE
  return (u16)(r >> 16);
}
__device__ __forceinline__ unsigned int pk2(float a, float b) {
  return (unsigned int)f2b(a) | ((unsigned int)f2b(b) << 16);
}
__device__ __forceinline__ void async16(const void* g, void* lds) {
  __builtin_amdgcn_global_load_lds((const __attribute__((address_space(1))) void*)g,
                                   (__attribute__((address_space(3))) void*)lds,
                                   16, 0, 0);
}

// ---------------- fused fp32 -> bf16 conversion (4 weight buffers, 1 launch) ----------------
struct F2BArgs {
  const float *s0, *s1, *s2, *s3;
  u16 *d0, *d1, *d2, *d3;
  int e0, e1, e2, e3;  // prefix ends, in 4-element groups
};
__global__ __launch_bounds__(256) void k_f2b4(F2BArgs a) {
  int g = blockIdx.x * 256 + threadIdx.x;
  const int stride = gridDim.x * 256;
  for (; g < a.e3; g += stride) {
    const float* s; u16* d; int off;
    if (g < a.e0)      { s = a.s0; d = a.d0; off = g; }
    else if (g < a.e1) { s = a.s1; d = a.d1; off = g - a.e0; }
    else if (g < a.e2) { s = a.s2; d = a.d2; off = g - a.e1; }
    else               { s = a.s3; d = a.d3; off = g - a.e2; }
    float4 v = *reinterpret_cast<const float4*>(s + (size_t)off * 4);
    u16 o[4] = { f2b(v.x), f2b(v.y), f2b(v.z), f2b(v.w) };
    *reinterpret_cast<uint2*>(d + (size_t)off * 4) = *reinterpret_cast<uint2*>(o);
  }
}

// ---------------- BK=32 2-blocks/CU soft-phase GEMM (qkv): C = A(MxK,fp32) * B(NxK)^T -----
// A consumed in fp32 DIRECTLY (x-conversion pass eliminated): reg-staged (issue float4
// loads at tile top for t+1, convert RNE + ds_write_b128 after MFMA clusters, lgkmcnt(0)
// before boundary barrier). B bf16 triple-slot via global_load_lds, staged 2 tiles ahead,
// counted vmcnt(BSTG) at boundary (B(t+2) stays in flight). 63 KB LDS = 2 blocks/CU.
// Swizzle: chunk XOR (row>>1)&3 (64 B rows) -> bank slots cover 8 positions, 2-way free.
// V-region output written TRANSPOSED directly into vtb (fused k_transpose).
template<int BM, int BN, int WN, int BSTG>
__global__ __launch_bounds__(512, 4) void k_gemmU(const float* __restrict__ Afp,
                                                  const u16* __restrict__ B,
                                                  u16* __restrict__ Cq,
                                                  u16* __restrict__ Ck, u16* __restrict__ Cvt,
                                                  int M, int N, int K, int nqc, int nkc) {
  constexpr int ALD = BM / 128;                      // A chunks per thread (=2)
  constexpr int NF = BN / WN / 16;                   // B frags per wave
  __shared__ __align__(16) u16 SA[2][BM * 32];       // double buffer
  __shared__ __align__(16) u16 SB[3][BN * 32];       // triple slot
  __shared__ __align__(16) u16 dscr[512];            // pad sink
  const int tid = threadIdx.x, lane = tid & 63, w = tid >> 6;
  const int wm = w / WN, wn = w % WN;
  const int g = lane >> 4, l15 = lane & 15;

  int ntx = gridDim.x;
  int id = blockIdx.y * ntx + blockIdx.x;
  int nwg = ntx * gridDim.y;
  if ((nwg & 7) == 0) { int q = nwg >> 3; id = (id & 7) * q + (id >> 3); }  // XCD swizzle
  const int m0 = (id / ntx) * BM, n0 = (id % ntx) * BN;
  const int NT = K >> 5;
  const int rsw = (l15 >> 1) & 3;                    // read-side row-XOR key

  auto loadA = [&](float4 fr[ALD][2], int kb) {      // issue fp32 loads (32B/chunk)
#pragma unroll
    for (int j = 0; j < ALD; ++j) {
      int c = j * 512 + tid;
      int r = c >> 2, cp = c & 3;
      const float* src = Afp + (size_t)(m0 + r) * K + kb + ((cp ^ ((r >> 1) & 3)) << 3);
      fr[j][0] = *reinterpret_cast<const float4*>(src);
      fr[j][1] = *reinterpret_cast<const float4*>(src + 4);
    }
  };
  auto writeA = [&](int buf, float4 fr[ALD][2]) {    // convert + ds_write_b128
#pragma unroll
    for (int j = 0; j < ALD; ++j) {
      int c = j * 512 + tid;
      const float* f0 = (const float*)&fr[j][0];
      const float* f1 = (const float*)&fr[j][1];
      u16 o[8];
#pragma unroll
      for (int e = 0; e < 4; ++e) { o[e] = f2b(f0[e]); o[4 + e] = f2b(f1[e]); }
      *reinterpret_cast<uint4*>((char*)SA[buf] + c * 16) = *reinterpret_cast<uint4*>(o);
    }
  };
  auto stageB = [&](int slot, int kb) {
#pragma unroll
    for (int j = 0; j < BSTG; ++j) {
      int c = j * 512 + tid;
      if (c < BN * 4) {
        int r = c >> 2, cp = c & 3;
        async16(B + (size_t)(n0 + r) * K + kb + ((cp ^ ((r >> 1) & 3)) << 3),
                (char*)SB[slot] + c * 16);
      } else {
        async16(B, (char*)dscr + lane * 16);         // uniform vmcnt pad (wave-uniform)
      }
    }
  };

  // prologue: A(0), A(1) reg-staged; B(0), B(1) async; leave B(1)'s loads in flight
  {
    float4 fr[ALD][2];
    loadA(fr, 0); writeA(0, fr);
    if (NT > 1) { loadA(fr, 32); writeA(1, fr); }
  }
  stageB(0, 0);
  if (NT > 1) stageB(1, 32);
  asm volatile("s_waitcnt lgkmcnt(0)" ::: "memory");
  if (NT > 1) asm volatile("s_waitcnt vmcnt(%0)" :: "n"(BSTG) : "memory");
  else        asm volatile("s_waitcnt vmcnt(0)" ::: "memory");
  __builtin_amdgcn_s_barrier();
  asm volatile("" ::: "memory");

  f32x4 acc[4][NF] = {};
  int c3 = 0;                                        // kt % 3 (B slot)
  for (int kt = 0; kt < NT; ++kt) {
    const int cur = kt & 1;
    const bool haveA = (kt + 1 < NT);
    float4 fra[ALD][2];
    if (haveA) loadA(fra, (kt + 1) * 32);            // issue early: covered by MFMA phase
    const char* bb = (const char*)SB[c3];
    bf16x8 bfr[NF];
#pragma unroll
    for (int n = 0; n < NF; ++n) {
      int row = wn * (BN / WN) + n * 16 + l15;
      bfr[n] = *(const bf16x8*)(bb + (size_t)row * 64 + ((g ^ rsw) << 4));
    }
    const char* ab = (const char*)SA[cur];
#pragma unroll
    for (int m = 0; m < 4; ++m) {
      int row = wm * 64 + m * 16 + l15;
      bf16x8 af = *(const bf16x8*)(ab + (size_t)row * 64 + ((g ^ rsw) << 4));
      __builtin_amdgcn_s_setprio(1);
#pragma unroll
      for (int n = 0; n < NF; ++n)
        acc[m][n] = __builtin_amdgcn_mfma_f32_16x16x32_bf16(af, bfr[n], acc[m][n], 0, 0, 0);
      __builtin_amdgcn_s_setprio(0);
    }
    if (haveA) writeA(cur ^ 1, fra);                 // convert + write into other A buffer
    int b2 = c3 + 2; if (b2 >= 3) b2 -= 3;
    if (kt + 2 < NT) stageB(b2, (kt + 2) * 32);
    asm volatile("s_waitcnt lgkmcnt(0)" ::: "memory");
    if (kt + 2 < NT)      asm volatile("s_waitcnt vmcnt(%0)" :: "n"(BSTG) : "memory");
    else if (kt + 1 < NT) asm volatile("s_waitcnt vmcnt(0)" ::: "memory");
    asm volatile("" ::: "memory");
    __builtin_amdgcn_s_barrier();
    asm volatile("" ::: "memory");
    c3 = (c3 == 2) ? 0 : c3 + 1;
  }

  const int er = g * 4;
#pragma unroll
  for (int n = 0; n < NF; ++n) {
    int col0 = n0 + wn * (BN / WN) + n * 16;         // 16-col frag never straddles a region
    if (col0 < nqc + nkc) {
      u16* dst; int stride, coff;
      if (col0 < nqc) { dst = Cq; stride = nqc; coff = 0; }
      else            { dst = Ck; stride = nkc; coff = nqc; }
#pragma unroll
      for (int m = 0; m < 4; ++m)
#pragma unroll
        for (int jj = 0; jj < 4; ++jj)
          dst[(size_t)(m0 + wm * 64 + m * 16 + er + jj) * stride + (col0 - coff) + l15] =
              f2b(acc[m][n][jj]);
    } else {
      // V region: write transposed into vtb [nkc][M] (rows er+0..3 are consecutive)
      int colV = col0 - (nqc + nkc) + l15;
#pragma unroll
      for (int m = 0; m < 4; ++m) {
        int row0 = m0 + wm * 64 + m * 16 + er;
        u16 ou[4] = { f2b(acc[m][n][0]), f2b(acc[m][n][1]),
                      f2b(acc[m][n][2]), f2b(acc[m][n][3]) };
        *reinterpret_cast<uint2*>(Cvt + (size_t)colV * M + row0) =
            *reinterpret_cast<uint2*>(ou);
      }
    }
  }
}

// ---------------- soft-phase 8-wave GEMM, BK=64 (round-7 proven; out-proj) ----------------
template<int BN, int NF, int BSTG, int SPLIT>
__global__ __launch_bounds__(512, 2) void k_gemmS(const u16* __restrict__ A,
                                                  const u16* __restrict__ B,
                                                  void* __restrict__ C0,
                                                  u16* __restrict__ Ck, u16* __restrict__ Cv,
                                                  int M, int N, int K, int nqc, int nkc) {
  __shared__ __align__(16) u16 SA[2][2][128 * 64];   // [buf][half] 64 KB
  __shared__ __align__(16) u16 SB[3][BN * 64];       // 3-buffer rotation
  __shared__ __align__(16) u16 dscr[512];
  const int tid = threadIdx.x, lane = tid & 63, w = tid >> 6;
  const int wm = w >> 1, wn = w & 1;                 // 4M x 2N wave grid
  const int g = lane >> 4, l15 = lane & 15;

  int ntx = gridDim.x;
  int id = blockIdx.y * ntx + blockIdx.x;
  int nwg = ntx * gridDim.y;
  if ((nwg & 7) == 0) { int q = nwg >> 3; id = (id & 7) * q + (id >> 3); }
  const int m0 = (id / ntx) * 256, n0 = (id % ntx) * BN;
  const int NT = K >> 6;

  auto stageA = [&](int buf, int half, int kb) {
#pragma unroll
    for (int j = 0; j < 2; ++j) {
      int c = j * 512 + tid;
      int r = c >> 3, cp = c & 7;
      async16(A + (size_t)(m0 + half * 128 + r) * K + kb + ((cp ^ (r & 7)) << 3),
              (char*)SA[buf][half] + c * 16);
    }
  };
  auto stageB = [&](int buf, int kb) {
#pragma unroll
    for (int j = 0; j < BSTG; ++j) {
      int c = j * 512 + tid;
      if (c < BN * 8) {
        int r = c >> 3, cp = c & 7;
        async16(B + (size_t)(n0 + r) * K + kb + ((cp ^ (r & 7)) << 3),
                (char*)SB[buf] + c * 16);
      } else {
        async16(B, (char*)dscr + lane * 16);
      }
    }
  };

  stageA(0, 0, 0); stageA(0, 1, 0);
  stageB(0, 0);
  if (NT > 1) stageB(1, 64);
  if constexpr (BSTG == 3) asm volatile("s_waitcnt vmcnt(3)" ::: "memory");
  else                     asm volatile("s_waitcnt vmcnt(2)" ::: "memory");
  __builtin_amdgcn_s_barrier();
  asm volatile("" ::: "memory");

  f32x4 acc[4][NF] = {};
  int c3 = 0;
  for (int kt = 0; kt < NT; ++kt) {
    const int cur = kt & 1;
    const char* bb = (const char*)SB[c3];
    bf16x8 bfr[NF][2];
#pragma unroll
    for (int n = 0; n < NF; ++n)
#pragma unroll
      for (int ks = 0; ks < 2; ++ks)
        bfr[n][ks] = *(const bf16x8*)(bb + (size_t)(wn * (BN / 2) + n * 16 + l15) * 128 +
                                      ((((ks << 2) | g) ^ (l15 & 7)) << 4));
    if (kt + 1 < NT) { stageA(cur ^ 1, 0, (kt + 1) * 64); stageA(cur ^ 1, 1, (kt + 1) * 64); }
    const char* ab = (const char*)SA[cur][wm >> 1];
    const int rb = (wm & 1) * 64;
#pragma unroll
    for (int m = 0; m < 4; ++m) {
      bf16x8 af[2];
#pragma unroll
      for (int ks = 0; ks < 2; ++ks)
        af[ks] = *(const bf16x8*)(ab + (size_t)(rb + m * 16 + l15) * 128 +
                                  ((((ks << 2) | g) ^ (l15 & 7)) << 4));
      __builtin_amdgcn_s_setprio(1);
#pragma unroll
      for (int n = 0; n < NF; ++n)
#pragma unroll
        for (int ks = 0; ks < 2; ++ks)
          acc[m][n] = __builtin_amdgcn_mfma_f32_16x16x32_bf16(af[ks], bfr[n][ks], acc[m][n],
                                                              0, 0, 0);
      __builtin_amdgcn_s_setprio(0);
    }
    int b2 = c3 + 2; if (b2 >= 3) b2 -= 3;
    if (kt + 2 < NT) stageB(b2, (kt + 2) * 64);
    asm volatile("" ::: "memory");
    if (kt + 2 < NT) {
      if constexpr (BSTG == 3) asm volatile("s_waitcnt vmcnt(3)" ::: "memory");
      else                     asm volatile("s_waitcnt vmcnt(2)" ::: "memory");
    } else {
      asm volatile("s_waitcnt vmcnt(0)" ::: "memory");
    }
    __builtin_amdgcn_s_barrier();
    asm volatile("" ::: "memory");
    c3 = (c3 == 2) ? 0 : c3 + 1;
  }

  const int er = g * 4;
  if constexpr (SPLIT == 0) {
    float* C = (float*)C0;
#pragma unroll
    for (int m = 0; m < 4; ++m)
#pragma unroll
      for (int n = 0; n < NF; ++n)
#pragma unroll
        for (int jj = 0; jj < 4; ++jj)
          C[(size_t)(m0 + wm * 64 + m * 16 + er + jj) * N + n0 + wn * (BN / 2) + n * 16 + l15] =
              acc[m][n][jj];
  } else {
#pragma unroll
    for (int n = 0; n < NF; ++n) {
      int col0 = n0 + wn * (BN / 2) + n * 16;
      u16* dst; int stride, coff;
      if (col0 < nqc)            { dst = (u16*)C0; stride = nqc; coff = 0; }
      else if (col0 < nqc + nkc) { dst = Ck;       stride = nkc; coff = nqc; }
      else                       { dst = Cv;       stride = nkc; coff = nqc + nkc; }
#pragma unroll
      for (int m = 0; m < 4; ++m)
#pragma unroll
        for (int jj = 0; jj < 4; ++jj)
          dst[(size_t)(m0 + wm * 64 + m * 16 + er + jj) * stride + (col0 - coff) + l15] =
              f2b(acc[m][n][jj]);
    }
  }
}

// ---------------- RMSNorm(offset) + RoPE for q AND k in one launch ----------------
__global__ __launch_bounds__(256) void k_normrope2(u16* __restrict__ qbuf, u16* __restrict__ kbuf,
                                                   const float* __restrict__ cosb,
                                                   const float* __restrict__ sinb,
                                                   const float* __restrict__ qw,
                                                   const float* __restrict__ kw,
                                                   int total, float qscale) {
  int wid = blockIdx.x * 4 + (threadIdx.x >> 6);
  int lane = threadIdx.x & 63;
  const int qn = total * 16;
  u16* base; const float* wgt; float ps; int t;
  if (wid < qn) {
    t = wid >> 4; int h = wid & 15;
    base = qbuf + (size_t)t * 4096 + h * 256;
    wgt = qw; ps = qscale;
  } else {
    wid -= qn;
    t = wid >> 2; int h = wid & 3;
    if (t >= total) return;
    base = kbuf + (size_t)t * 512 + h * 128;
    wgt = kw; ps = 1.0f;
  }
  float a = b2f(base[lane]), b = b2f(base[lane + 64]);
  float ss = a * a + b * b;
#pragma unroll
  for (int m = 32; m >= 1; m >>= 1) ss += __shfl_xor(ss, m, 64);
  float r = rsqrtf(ss * (1.0f / 128.0f) + 1e-6f);
  float qa = (1.0f + wgt[lane]) * a * r;
  float qb = (1.0f + wgt[lane + 64]) * b * r;
  const float* cr = cosb + (size_t)t * 128;
  const float* sr = sinb + (size_t)t * 128;
  float oa = (qa * cr[lane] - qb * sr[lane]) * ps;
  float ob = (qb * cr[lane + 64] + qa * sr[lane + 64]) * ps;
  base[lane] = f2b(oa);
  base[lane + 64] = f2b(ob);
}

// ---------------- flash attention + gate: 8-wave block, LDS-staged K/V, 80 KB, 2 blk/CU ----
__global__ __launch_bounds__(512) void k_attn(const u16* __restrict__ qg,  // total x 4096
                                              const u16* __restrict__ kb,  // total x 512
                                              const u16* __restrict__ vt,  // 512 x total
                                              u16* __restrict__ outg,      // total x 2048
                                              const int* __restrict__ cu, int n_seq, int total) {
  __shared__ __align__(16) u16 Ks[2][64 * 128];   // 32 KB
  __shared__ __align__(16) u16 Vs[2][128 * 64];   // 32 KB
  __shared__ __align__(16) u16 Ps[8][16][64];     // 16 KB, XOR-swizzled P bounce
  const int tid = threadIdx.x, lane = tid & 63, w = tid >> 6;  // w = 0..7
  const int h = blockIdx.y, kh = h >> 2;
  const int g = lane >> 4, l15 = lane & 15;

  int bx = blockIdx.x, qt = bx;
  int nbx = gridDim.x;
  int per = total / n_seq;
  if (per * n_seq == total && (per & 127) == 0 && nbx % n_seq == 0) {
    int tps = per >> 7;
    int seg = bx % n_seq;
    qt = seg * tps + (tps - 1 - bx / n_seq);
  }
  const int qb0 = qt * 128;

  int seg_start = 0, seg_end = total;
  for (int s = 0; s < n_seq; ++s) {
    int a = cu[s], b = cu[s + 1];
    if (qb0 >= a && qb0 < b) { seg_start = a; seg_end = b; }
  }
  const int qr0 = qb0 + w * 16;
  const int qrow = qr0 + l15;

  bf16x8 qf[4];
#pragma unroll
  for (int cc = 0; cc < 4; ++cc)
    qf[cc] = *reinterpret_cast<const bf16x8*>(qg + (size_t)qrow * 4096 + h * 256 + cc * 32 + g * 8);

  int blk_end = qb0 + 128; if (blk_end > seg_end) blk_end = seg_end;
  const int NT = (blk_end - seg_start + 63) >> 6;
  int my_end = qr0 + 16; if (my_end > seg_end) my_end = seg_end;
  const int myNT = (my_end - seg_start + 63) >> 6;

  f32x4 o[8] = {};
  float mrow = -1e30f, lrow = 0.f;
  char* prow = (char*)&Ps[w][l15][0];               // 128 B row stride
  const int pswz = (l15 & 7) << 4;

  {
    const int kv0 = seg_start;
#pragma unroll
    for (int i = 0; i < 2; ++i) {
      int c = i * 512 + tid;
      int r = c >> 4, k16 = c & 15;
      async16(kb + (size_t)(kv0 + r) * 512 + kh * 128 + ((k16 ^ (r & 7)) << 3),
              (char*)Ks[0] + c * 16);
      int rv = c >> 3, c8 = c & 7;
      async16(vt + (size_t)(kh * 128 + rv) * total + kv0 + ((c8 ^ (rv & 7)) << 3),
              (char*)Vs[0] + c * 16);
    }
  }
  __syncthreads();

  int cur = 0;
  for (int t = 0; t < NT; ++t) {
    if (t + 1 < NT) {
      const int kv0 = seg_start + (t + 1) * 64;
#pragma unroll
      for (int i = 0; i < 2; ++i) {
        int c = i * 512 + tid;
        int r = c >> 4, k16 = c & 15;
        async16(kb + (size_t)(kv0 + r) * 512 + kh * 128 + ((k16 ^ (r & 7)) << 3),
                (char*)Ks[cur ^ 1] + c * 16);
        int rv = c >> 3, c8 = c & 7;
        async16(vt + (size_t)(kh * 128 + rv) * total + kv0 + ((c8 ^ (rv & 7)) << 3),
                (char*)Vs[cur ^ 1] + c * 16);
      }
    }
    if (t < myNT) {
      const int kv0 = seg_start + t * 64;
      f32x4 sa[4] = {};
      __builtin_amdgcn_s_setprio(1);
#pragma unroll
      for (int cc = 0; cc < 4; ++cc)
#pragma unroll
        for (int s = 0; s < 4; ++s) {
          bf16x8 kf = *reinterpret_cast<const bf16x8*>(
              (char*)Ks[cur] + (s * 16 + l15) * 256 + ((((cc << 2) | g) ^ (l15 & 7)) << 4));
          sa[s] = __builtin_amdgcn_mfma_f32_16x16x32_bf16(kf, qf[cc], sa[s], 0, 0, 0);
        }
      __builtin_amdgcn_s_setprio(0);
      float sv[16];
#pragma unroll
      for (int s = 0; s < 4; ++s)
#pragma unroll
        for (int j = 0; j < 4; ++j)
          sv[s * 4 + j] = (kv0 + s * 16 + g * 4 + j > qrow) ? -1e30f : sa[s][j];
      float pm = sv[0];
#pragma unroll
      for (int j = 1; j < 16; ++j) pm = fmaxf(pm, sv[j]);
      pm = fmaxf(pm, __shfl_xor(pm, 16));
      pm = fmaxf(pm, __shfl_xor(pm, 32));
      if (pm > mrow + 11.5f) {
        float fs = __builtin_amdgcn_exp2f(mrow - pm);
        lrow *= fs;
#pragma unroll
        for (int db = 0; db < 8; ++db)
#pragma unroll
          for (int j = 0; j < 4; ++j) o[db][j] *= fs;
        mrow = pm;
      }
      float p[16];
#pragma unroll
      for (int j = 0; j < 16; ++j)
        p[j] = (sv[j] > -1e29f) ? __builtin_amdgcn_exp2f(sv[j] - mrow) : 0.0f;
      float ps = 0.f;
#pragma unroll
      for (int j = 0; j < 16; ++j) ps += p[j];
      ps += __shfl_xor(ps, 16);
      ps += __shfl_xor(ps, 32);
      lrow += ps;
#pragma unroll
      for (int s = 0; s < 4; ++s) {
        uint2 pw = { pk2(p[s * 4], p[s * 4 + 1]), pk2(p[s * 4 + 2], p[s * 4 + 3]) };
        *reinterpret_cast<uint2*>(prow + ((s * 32 + g * 8) ^ pswz)) = pw;
      }
      asm volatile("" ::: "memory");
      __builtin_amdgcn_s_setprio(1);
#pragma unroll
      for (int half = 0; half < 2; ++half) {
        bf16x8 pf = *reinterpret_cast<const bf16x8*>(prow + ((half * 64 + g * 16) ^ pswz));
#pragma unroll
        for (int db = 0; db < 8; ++db) {
          bf16x8 vf = *reinterpret_cast<const bf16x8*>(
              (char*)Vs[cur] + (db * 16 + l15) * 128 + ((((half << 2) | g) ^ (l15 & 7)) << 4));
          o[db] = __builtin_amdgcn_mfma_f32_16x16x32_bf16(vf, pf, o[db], 0, 0, 0);
        }
      }
      __builtin_amdgcn_s_setprio(0);
    }
    __syncthreads();
    cur ^= 1;
  }

  const float invL = 1.0f / lrow;
#pragma unroll
  for (int db = 0; db < 8; ++db) {
    int d0 = db * 16 + g * 4;
    uint2 gw = *reinterpret_cast<const uint2*>(qg + (size_t)qrow * 4096 + h * 256 + 128 + d0);
    u16 gu[4] = { (u16)(gw.x & 0xffff), (u16)(gw.x >> 16),
                  (u16)(gw.y & 0xffff), (u16)(gw.y >> 16) };
    u16 ou[4];
#pragma unroll
    for (int j = 0; j < 4; ++j) {
      float gate = b2f(gu[j]);
      float sig = 1.0f / (1.0f + __expf(-gate));
      ou[j] = f2b(o[db][j] * invL * sig);
    }
    *reinterpret_cast<uint2*>(outg + (size_t)qrow * 2048 + h * 128 + d0) =
        *reinterpret_cast<uint2*>(ou);
  }
}

extern "C" void kernel_launch(void* const* d_in, const int* in_sizes, int n_in,
                              void* d_out, int out_size, void* d_ws, size_t ws_size,
                              hipStream_t stream) {
  const float* x    = (const float*)d_in[0];
  const float* cosb = (const float*)d_in[1];
  const float* sinb = (const float*)d_in[2];
  const float* Wq   = (const float*)d_in[3];
  const float* Wk   = (const float*)d_in[4];
  const float* Wv   = (const float*)d_in[5];
  const float* Wo   = (const float*)d_in[6];
  const float* qnw  = (const float*)d_in[7];
  const float* knw  = (const float*)d_in[8];
  const int*   cu   = (const int*)d_in[9];
  const int n_seq = in_sizes[9] - 1;

  const int hidden = 2048, H = 16, KVH = 4, D = 128;
  const int total = in_sizes[0] / hidden;  // 4096
  const int NQ = H * D * 2;                // 4096
  const int NKV = KVH * D;                 // 512

  char* ws = (char*)d_ws;
  size_t off = 0;
  auto alloc = [&](size_t elems) {
    u16* p = (u16*)(ws + off);
    off += elems * 2;
    off = (off + 255) & ~(size_t)255;
    return p;
  };
  u16* Wqb  = alloc((size_t)NQ * hidden);    // Wqb|Wkb|Wvb contiguous => merged B (5120 x 2048)
  u16* Wkb  = alloc((size_t)NKV * hidden);
  u16* Wvb  = alloc((size_t)NKV * hidden);
  u16* Wob  = alloc((size_t)hidden * (H * D));
  u16* qgb  = alloc((size_t)total * NQ);
  u16* kbuf = alloc((size_t)total * NKV);
  u16* vtb  = alloc((size_t)total * NKV);    // V^T, written directly by qkv GEMM epilogue
  u16* attg = Wqb;  // alias: Wqb dead after the qkv GEMM

  // fused bf16 conversion of the 4 weight matrices (x stays fp32; consumed by k_gemmU)
  F2BArgs fa;
  fa.s0 = Wq;  fa.s1 = Wk;  fa.s2 = Wv;  fa.s3 = Wo;
  fa.d0 = Wqb; fa.d1 = Wkb; fa.d2 = Wvb; fa.d3 = Wob;
  int g0 = NQ * hidden / 4, g1 = NKV * hidden / 4, g2 = NKV * hidden / 4;
  int g3 = hidden * H * D / 4;
  fa.e0 = g0; fa.e1 = fa.e0 + g1; fa.e2 = fa.e1 + g2; fa.e3 = fa.e2 + g3;
  k_f2b4<<<2048, 256, 0, stream>>>(fa);

  // fused qkv projection: A = x in fp32 (reg-staged conversion); BM=256 BN=160 WN=2
  // => 32x16 = 512 blocks = 2 blocks/CU, 1 round. V written transposed into vtb.
  const int Nqkv = NQ + 2 * NKV;  // 5120
  k_gemmU<256, 160, 2, 2><<<dim3(Nqkv / 160, total / 256), 512, 0, stream>>>(
      x, Wqb, qgb, kbuf, vtb, total, Nqkv, hidden, NQ, NKV);
  const float qscale = 0.08838834764831845f * 1.4426950408889634f;  // 1/sqrt(D) * log2(e)
  k_normrope2<<<total * (H + KVH) / 4, 256, 0, stream>>>(qgb, kbuf, cosb, sinb, qnw, knw,
                                                         total, qscale);
  k_attn<<<dim3(total / 128, H), 512, 0, stream>>>(qgb, kbuf, vtb, attg, cu, n_seq, total);
  // out = attg @ Wo^T: round-7 proven soft-phase BK=64, BN=128 => 256 blocks = 1 round
  k_gemmS<128, 4, 2, 0><<<dim3(hidden / 128, total / 256), 512, 0, stream>>>(
      attg, Wob, (float*)d_out, nullptr, nullptr, total, hidden, H * D, 0, 0);
}

// Round 17
// 225.589 us; speedup vs baseline: 1.5838x; 1.5838x over previous
//
#include <hip/hip_runtime.h>
#include <stdint.h>

typedef unsigned short u16;
typedef __bf16 bf16_t;
typedef bf16_t bf16x8 __attribute__((ext_vector_type(8)));
typedef float f32x4 __attribute__((ext_vector_type(4)));

__device__ __forceinline__ float b2f(u16 u) {
  union { unsigned int i; float f; } v; v.i = ((unsigned int)u) << 16; return v.f;
}
__device__ __forceinline__ u16 f2b(float f) {
  union { float f; unsigned int i; } v; v.f = f;
  unsigned int r = v.i + 0x7fffu + ((v.i >> 16) & 1u);  // RNE
  return (u16)(r >> 16);
}
__device__ __forceinline__ unsigned int pk2(float a, float b) {
  return (unsigned int)f2b(a) | ((unsigned int)f2b(b) << 16);
}
__device__ __forceinline__ void async16(const void* g, void* lds) {
  __builtin_amdgcn_global_load_lds((const __attribute__((address_space(1))) void*)g,
                                   (__attribute__((address_space(3))) void*)lds,
                                   16, 0, 0);
}

// ---------------- fused fp32 -> bf16 conversion (5 buffers, 1 launch) ----------------
struct F2BArgs {
  const float *s0, *s1, *s2, *s3, *s4;
  u16 *d0, *d1, *d2, *d3, *d4;
  int e0, e1, e2, e3, e4;  // prefix ends, in 4-element groups
};
__global__ __launch_bounds__(256) void k_f2b5(F2BArgs a) {
  int g = blockIdx.x * 256 + threadIdx.x;
  const int stride = gridDim.x * 256;
  for (; g < a.e4; g += stride) {
    const float* s; u16* d; int off;
    if (g < a.e0)      { s = a.s0; d = a.d0; off = g; }
    else if (g < a.e1) { s = a.s1; d = a.d1; off = g - a.e0; }
    else if (g < a.e2) { s = a.s2; d = a.d2; off = g - a.e1; }
    else if (g < a.e3) { s = a.s3; d = a.d3; off = g - a.e2; }
    else               { s = a.s4; d = a.d4; off = g - a.e3; }
    float4 v = *reinterpret_cast<const float4*>(s + (size_t)off * 4);
    u16 o[4] = { f2b(v.x), f2b(v.y), f2b(v.z), f2b(v.w) };
    *reinterpret_cast<uint2*>(d + (size_t)off * 4) = *reinterpret_cast<uint2*>(o);
  }
}

// ---------------- BK=32 2-blocks/CU soft-phase GEMM (qkv): C = A(MxK) * B(NxK)^T ----------
// A double-buffered, B triple-slot staged 2 K-tiles ahead; one counted vmcnt(BSTG) +
// barrier per K-tile (B(t+2) stays in flight). 63 KB LDS = 2 blocks/CU (proven r10-r12).
// Swizzle: chunk XOR (row>>1)&3 (64 B rows) -> bank slots cover 8 positions, 2-way free.
template<int BM, int BN, int WN, int BSTG, int SPLIT>
__global__ __launch_bounds__(512, 4) void k_gemmU(const u16* __restrict__ A,
                                                  const u16* __restrict__ B,
                                                  void* __restrict__ C0,
                                                  u16* __restrict__ Ck, u16* __restrict__ Cv,
                                                  int M, int N, int K, int nqc, int nkc) {
  constexpr int ALD = BM / 128;                      // A chunks per thread
  constexpr int NF = BN / WN / 16;                   // B frags per wave
  __shared__ __align__(16) u16 SA[2][BM * 32];       // double buffer
  __shared__ __align__(16) u16 SB[3][BN * 32];       // triple slot
  __shared__ __align__(16) u16 dscr[512];            // pad sink
  const int tid = threadIdx.x, lane = tid & 63, w = tid >> 6;
  const int wm = w / WN, wn = w % WN;
  const int g = lane >> 4, l15 = lane & 15;

  int ntx = gridDim.x;
  int id = blockIdx.y * ntx + blockIdx.x;
  int nwg = ntx * gridDim.y;
  if ((nwg & 7) == 0) { int q = nwg >> 3; id = (id & 7) * q + (id >> 3); }  // XCD swizzle
  const int m0 = (id / ntx) * BM, n0 = (id % ntx) * BN;
  const int NT = K >> 5;
  const int rsw = (l15 >> 1) & 3;                    // read-side row-XOR key

  auto stageA = [&](int buf, int kb) {
#pragma unroll
    for (int j = 0; j < ALD; ++j) {
      int c = j * 512 + tid;
      int r = c >> 2, cp = c & 3;
      async16(A + (size_t)(m0 + r) * K + kb + ((cp ^ ((r >> 1) & 3)) << 3),
              (char*)SA[buf] + c * 16);
    }
  };
  auto stageB = [&](int slot, int kb) {
#pragma unroll
    for (int j = 0; j < BSTG; ++j) {
      int c = j * 512 + tid;
      if (c < BN * 4) {
        int r = c >> 2, cp = c & 3;
        async16(B + (size_t)(n0 + r) * K + kb + ((cp ^ ((r >> 1) & 3)) << 3),
                (char*)SB[slot] + c * 16);
      } else {
        async16(B, (char*)dscr + lane * 16);         // uniform vmcnt pad (wave-uniform)
      }
    }
  };

  // prologue: A(0), B(0), B(1); leave B(1)'s loads in flight
  stageA(0, 0);
  stageB(0, 0);
  if (NT > 1) stageB(1, 32);
  if (NT > 1) asm volatile("s_waitcnt vmcnt(%0)" :: "n"(BSTG) : "memory");
  else        asm volatile("s_waitcnt vmcnt(0)" ::: "memory");
  __builtin_amdgcn_s_barrier();
  asm volatile("" ::: "memory");

  f32x4 acc[4][NF] = {};
  int c3 = 0;                                        // kt % 3
  for (int kt = 0; kt < NT; ++kt) {
    const int cur = kt & 1;
    const char* bb = (const char*)SB[c3];
    bf16x8 bfr[NF];
#pragma unroll
    for (int n = 0; n < NF; ++n) {
      int row = wn * (BN / WN) + n * 16 + l15;
      bfr[n] = *(const bf16x8*)(bb + (size_t)row * 64 + ((g ^ rsw) << 4));
    }
    if (kt + 1 < NT) stageA(cur ^ 1, (kt + 1) * 32);
    const char* ab = (const char*)SA[cur];
#pragma unroll
    for (int m = 0; m < 4; ++m) {
      int row = wm * 64 + m * 16 + l15;
      bf16x8 af = *(const bf16x8*)(ab + (size_t)row * 64 + ((g ^ rsw) << 4));
      __builtin_amdgcn_s_setprio(1);
#pragma unroll
      for (int n = 0; n < NF; ++n)
        acc[m][n] = __builtin_amdgcn_mfma_f32_16x16x32_bf16(af, bfr[n], acc[m][n], 0, 0, 0);
      __builtin_amdgcn_s_setprio(0);
    }
    int b2 = c3 + 2; if (b2 >= 3) b2 -= 3;
    if (kt + 2 < NT) stageB(b2, (kt + 2) * 32);
    asm volatile("" ::: "memory");
    if (kt + 2 < NT)      asm volatile("s_waitcnt vmcnt(%0)" :: "n"(BSTG) : "memory");
    else if (kt + 1 < NT) asm volatile("s_waitcnt vmcnt(0)" ::: "memory");
    asm volatile("" ::: "memory");
    __builtin_amdgcn_s_barrier();
    asm volatile("" ::: "memory");
    c3 = (c3 == 2) ? 0 : c3 + 1;
  }

  const int er = g * 4;
  if constexpr (SPLIT == 0) {
    float* C = (float*)C0;
#pragma unroll
    for (int m = 0; m < 4; ++m)
#pragma unroll
      for (int n = 0; n < NF; ++n)
#pragma unroll
        for (int jj = 0; jj < 4; ++jj)
          C[(size_t)(m0 + wm * 64 + m * 16 + er + jj) * N + n0 + wn * (BN / WN) + n * 16 + l15] =
              acc[m][n][jj];
  } else {
#pragma unroll
    for (int n = 0; n < NF; ++n) {
      int col0 = n0 + wn * (BN / WN) + n * 16;       // 16-col frag never straddles a region
      u16* dst; int stride, coff;
      if (col0 < nqc)            { dst = (u16*)C0; stride = nqc; coff = 0; }
      else if (col0 < nqc + nkc) { dst = Ck;       stride = nkc; coff = nqc; }
      else                       { dst = Cv;       stride = nkc; coff = nqc + nkc; }
#pragma unroll
      for (int m = 0; m < 4; ++m)
#pragma unroll
        for (int jj = 0; jj < 4; ++jj)
          dst[(size_t)(m0 + wm * 64 + m * 16 + er + jj) * stride + (col0 - coff) + l15] =
              f2b(acc[m][n][jj]);
    }
  }
}

// ---------------- soft-phase 8-wave GEMM, BK=64 (round-7 proven; out-proj) ----------------
template<int BN, int NF, int BSTG, int SPLIT>
__global__ __launch_bounds__(512, 2) void k_gemmS(const u16* __restrict__ A,
                                                  const u16* __restrict__ B,
                                                  void* __restrict__ C0,
                                                  u16* __restrict__ Ck, u16* __restrict__ Cv,
                                                  int M, int N, int K, int nqc, int nkc) {
  __shared__ __align__(16) u16 SA[2][2][128 * 64];   // [buf][half] 64 KB
  __shared__ __align__(16) u16 SB[3][BN * 64];       // 3-buffer rotation
  __shared__ __align__(16) u16 dscr[512];
  const int tid = threadIdx.x, lane = tid & 63, w = tid >> 6;
  const int wm = w >> 1, wn = w & 1;                 // 4M x 2N wave grid
  const int g = lane >> 4, l15 = lane & 15;

  int ntx = gridDim.x;
  int id = blockIdx.y * ntx + blockIdx.x;
  int nwg = ntx * gridDim.y;
  if ((nwg & 7) == 0) { int q = nwg >> 3; id = (id & 7) * q + (id >> 3); }
  const int m0 = (id / ntx) * 256, n0 = (id % ntx) * BN;
  const int NT = K >> 6;

  auto stageA = [&](int buf, int half, int kb) {
#pragma unroll
    for (int j = 0; j < 2; ++j) {
      int c = j * 512 + tid;
      int r = c >> 3, cp = c & 7;
      async16(A + (size_t)(m0 + half * 128 + r) * K + kb + ((cp ^ (r & 7)) << 3),
              (char*)SA[buf][half] + c * 16);
    }
  };
  auto stageB = [&](int buf, int kb) {
#pragma unroll
    for (int j = 0; j < BSTG; ++j) {
      int c = j * 512 + tid;
      if (c < BN * 8) {
        int r = c >> 3, cp = c & 7;
        async16(B + (size_t)(n0 + r) * K + kb + ((cp ^ (r & 7)) << 3),
                (char*)SB[buf] + c * 16);
      } else {
        async16(B, (char*)dscr + lane * 16);
      }
    }
  };

  stageA(0, 0, 0); stageA(0, 1, 0);
  stageB(0, 0);
  if (NT > 1) stageB(1, 64);
  if constexpr (BSTG == 3) asm volatile("s_waitcnt vmcnt(3)" ::: "memory");
  else                     asm volatile("s_waitcnt vmcnt(2)" ::: "memory");
  __builtin_amdgcn_s_barrier();
  asm volatile("" ::: "memory");

  f32x4 acc[4][NF] = {};
  int c3 = 0;
  for (int kt = 0; kt < NT; ++kt) {
    const int cur = kt & 1;
    const char* bb = (const char*)SB[c3];
    bf16x8 bfr[NF][2];
#pragma unroll
    for (int n = 0; n < NF; ++n)
#pragma unroll
      for (int ks = 0; ks < 2; ++ks)
        bfr[n][ks] = *(const bf16x8*)(bb + (size_t)(wn * (BN / 2) + n * 16 + l15) * 128 +
                                      ((((ks << 2) | g) ^ (l15 & 7)) << 4));
    if (kt + 1 < NT) { stageA(cur ^ 1, 0, (kt + 1) * 64); stageA(cur ^ 1, 1, (kt + 1) * 64); }
    const char* ab = (const char*)SA[cur][wm >> 1];
    const int rb = (wm & 1) * 64;
#pragma unroll
    for (int m = 0; m < 4; ++m) {
      bf16x8 af[2];
#pragma unroll
      for (int ks = 0; ks < 2; ++ks)
        af[ks] = *(const bf16x8*)(ab + (size_t)(rb + m * 16 + l15) * 128 +
                                  ((((ks << 2) | g) ^ (l15 & 7)) << 4));
      __builtin_amdgcn_s_setprio(1);
#pragma unroll
      for (int n = 0; n < NF; ++n)
#pragma unroll
        for (int ks = 0; ks < 2; ++ks)
          acc[m][n] = __builtin_amdgcn_mfma_f32_16x16x32_bf16(af[ks], bfr[n][ks], acc[m][n],
                                                              0, 0, 0);
      __builtin_amdgcn_s_setprio(0);
    }
    int b2 = c3 + 2; if (b2 >= 3) b2 -= 3;
    if (kt + 2 < NT) stageB(b2, (kt + 2) * 64);
    asm volatile("" ::: "memory");
    if (kt + 2 < NT) {
      if constexpr (BSTG == 3) asm volatile("s_waitcnt vmcnt(3)" ::: "memory");
      else                     asm volatile("s_waitcnt vmcnt(2)" ::: "memory");
    } else {
      asm volatile("s_waitcnt vmcnt(0)" ::: "memory");
    }
    __builtin_amdgcn_s_barrier();
    asm volatile("" ::: "memory");
    c3 = (c3 == 2) ? 0 : c3 + 1;
  }

  const int er = g * 4;
  if constexpr (SPLIT == 0) {
    float* C = (float*)C0;
#pragma unroll
    for (int m = 0; m < 4; ++m)
#pragma unroll
      for (int n = 0; n < NF; ++n)
#pragma unroll
        for (int jj = 0; jj < 4; ++jj)
          C[(size_t)(m0 + wm * 64 + m * 16 + er + jj) * N + n0 + wn * (BN / 2) + n * 16 + l15] =
              acc[m][n][jj];
  } else {
#pragma unroll
    for (int n = 0; n < NF; ++n) {
      int col0 = n0 + wn * (BN / 2) + n * 16;
      u16* dst; int stride, coff;
      if (col0 < nqc)            { dst = (u16*)C0; stride = nqc; coff = 0; }
      else if (col0 < nqc + nkc) { dst = Ck;       stride = nkc; coff = nqc; }
      else                       { dst = Cv;       stride = nkc; coff = nqc + nkc; }
#pragma unroll
      for (int m = 0; m < 4; ++m)
#pragma unroll
        for (int jj = 0; jj < 4; ++jj)
          dst[(size_t)(m0 + wm * 64 + m * 16 + er + jj) * stride + (col0 - coff) + l15] =
              f2b(acc[m][n][jj]);
    }
  }
}

// ---------------- RMSNorm(offset) + RoPE for q AND k in one launch ----------------
__global__ __launch_bounds__(256) void k_normrope2(u16* __restrict__ qbuf, u16* __restrict__ kbuf,
                                                   const float* __restrict__ cosb,
                                                   const float* __restrict__ sinb,
                                                   const float* __restrict__ qw,
                                                   const float* __restrict__ kw,
                                                   int total, float qscale) {
  int wid = blockIdx.x * 4 + (threadIdx.x >> 6);
  int lane = threadIdx.x & 63;
  const int qn = total * 16;
  u16* base; const float* wgt; float ps; int t;
  if (wid < qn) {
    t = wid >> 4; int h = wid & 15;
    base = qbuf + (size_t)t * 4096 + h * 256;
    wgt = qw; ps = qscale;
  } else {
    wid -= qn;
    t = wid >> 2; int h = wid & 3;
    if (t >= total) return;
    base = kbuf + (size_t)t * 512 + h * 128;
    wgt = kw; ps = 1.0f;
  }
  float a = b2f(base[lane]), b = b2f(base[lane + 64]);
  float ss = a * a + b * b;
#pragma unroll
  for (int m = 32; m >= 1; m >>= 1) ss += __shfl_xor(ss, m, 64);
  float r = rsqrtf(ss * (1.0f / 128.0f) + 1e-6f);
  float qa = (1.0f + wgt[lane]) * a * r;
  float qb = (1.0f + wgt[lane + 64]) * b * r;
  const float* cr = cosb + (size_t)t * 128;
  const float* sr = sinb + (size_t)t * 128;
  float oa = (qa * cr[lane] - qb * sr[lane]) * ps;
  float ob = (qb * cr[lane + 64] + qa * sr[lane + 64]) * ps;
  base[lane] = f2b(oa);
  base[lane + 64] = f2b(ob);
}

// ---------------- transpose (rows x cols) -> (cols x rows), bf16 ----------------
__global__ __launch_bounds__(256) void k_transpose(const u16* __restrict__ src,
                                                   u16* __restrict__ dst, int rows, int cols) {
  __shared__ u16 tile[32][33];
  int bx = blockIdx.x * 32, by = blockIdx.y * 32;
  int tx = threadIdx.x & 31, ty = threadIdx.x >> 5;
#pragma unroll
  for (int i = 0; i < 4; ++i)
    tile[ty + i * 8][tx] = src[(size_t)(bx + ty + i * 8) * cols + by + tx];
  __syncthreads();
#pragma unroll
  for (int i = 0; i < 4; ++i)
    dst[(size_t)(by + ty + i * 8) * rows + bx + tx] = tile[tx][ty + i * 8];
}

// ---------------- flash attention + gate: 8-wave block, LDS-staged K/V, 80 KB, 2 blk/CU ----
__global__ __launch_bounds__(512) void k_attn(const u16* __restrict__ qg,  // total x 4096
                                              const u16* __restrict__ kb,  // total x 512
                                              const u16* __restrict__ vt,  // 512 x total
                                              u16* __restrict__ outg,      // total x 2048
                                              const int* __restrict__ cu, int n_seq, int total) {
  __shared__ __align__(16) u16 Ks[2][64 * 128];   // 32 KB
  __shared__ __align__(16) u16 Vs[2][128 * 64];   // 32 KB
  __shared__ __align__(16) u16 Ps[8][16][64];     // 16 KB, XOR-swizzled P bounce
  const int tid = threadIdx.x, lane = tid & 63, w = tid >> 6;  // w = 0..7
  const int h = blockIdx.y, kh = h >> 2;
  const int g = lane >> 4, l15 = lane & 15;

  int bx = blockIdx.x, qt = bx;
  int nbx = gridDim.x;
  int per = total / n_seq;
  if (per * n_seq == total && (per & 127) == 0 && nbx % n_seq == 0) {
    int tps = per >> 7;
    int seg = bx % n_seq;
    qt = seg * tps + (tps - 1 - bx / n_seq);
  }
  const int qb0 = qt * 128;

  int seg_start = 0, seg_end = total;
  for (int s = 0; s < n_seq; ++s) {
    int a = cu[s], b = cu[s + 1];
    if (qb0 >= a && qb0 < b) { seg_start = a; seg_end = b; }
  }
  const int qr0 = qb0 + w * 16;
  const int qrow = qr0 + l15;

  bf16x8 qf[4];
#pragma unroll
  for (int cc = 0; cc < 4; ++cc)
    qf[cc] = *reinterpret_cast<const bf16x8*>(qg + (size_t)qrow * 4096 + h * 256 + cc * 32 + g * 8);

  int blk_end = qb0 + 128; if (blk_end > seg_end) blk_end = seg_end;
  const int NT = (blk_end - seg_start + 63) >> 6;
  int my_end = qr0 + 16; if (my_end > seg_end) my_end = seg_end;
  const int myNT = (my_end - seg_start + 63) >> 6;

  f32x4 o[8] = {};
  float mrow = -1e30f, lrow = 0.f;
  char* prow = (char*)&Ps[w][l15][0];               // 128 B row stride
  const int pswz = (l15 & 7) << 4;

  {
    const int kv0 = seg_start;
#pragma unroll
    for (int i = 0; i < 2; ++i) {
      int c = i * 512 + tid;
      int r = c >> 4, k16 = c & 15;
      async16(kb + (size_t)(kv0 + r) * 512 + kh * 128 + ((k16 ^ (r & 7)) << 3),
              (char*)Ks[0] + c * 16);
      int rv = c >> 3, c8 = c & 7;
      async16(vt + (size_t)(kh * 128 + rv) * total + kv0 + ((c8 ^ (rv & 7)) << 3),
              (char*)Vs[0] + c * 16);
    }
  }
  __syncthreads();

  int cur = 0;
  for (int t = 0; t < NT; ++t) {
    if (t + 1 < NT) {
      const int kv0 = seg_start + (t + 1) * 64;
#pragma unroll
      for (int i = 0; i < 2; ++i) {
        int c = i * 512 + tid;
        int r = c >> 4, k16 = c & 15;
        async16(kb + (size_t)(kv0 + r) * 512 + kh * 128 + ((k16 ^ (r & 7)) << 3),
                (char*)Ks[cur ^ 1] + c * 16);
        int rv = c >> 3, c8 = c & 7;
        async16(vt + (size_t)(kh * 128 + rv) * total + kv0 + ((c8 ^ (rv & 7)) << 3),
                (char*)Vs[cur ^ 1] + c * 16);
      }
    }
    if (t < myNT) {
      const int kv0 = seg_start + t * 64;
      f32x4 sa[4] = {};
      __builtin_amdgcn_s_setprio(1);
#pragma unroll
      for (int cc = 0; cc < 4; ++cc)
#pragma unroll
        for (int s = 0; s < 4; ++s) {
          bf16x8 kf = *reinterpret_cast<const bf16x8*>(
              (char*)Ks[cur] + (s * 16 + l15) * 256 + ((((cc << 2) | g) ^ (l15 & 7)) << 4));
          sa[s] = __builtin_amdgcn_mfma_f32_16x16x32_bf16(kf, qf[cc], sa[s], 0, 0, 0);
        }
      __builtin_amdgcn_s_setprio(0);
      float sv[16];
#pragma unroll
      for (int s = 0; s < 4; ++s)
#pragma unroll
        for (int j = 0; j < 4; ++j)
          sv[s * 4 + j] = (kv0 + s * 16 + g * 4 + j > qrow) ? -1e30f : sa[s][j];
      float pm = sv[0];
#pragma unroll
      for (int j = 1; j < 16; ++j) pm = fmaxf(pm, sv[j]);
      pm = fmaxf(pm, __shfl_xor(pm, 16));
      pm = fmaxf(pm, __shfl_xor(pm, 32));
      if (pm > mrow + 11.5f) {
        float fs = __builtin_amdgcn_exp2f(mrow - pm);
        lrow *= fs;
#pragma unroll
        for (int db = 0; db < 8; ++db)
#pragma unroll
          for (int j = 0; j < 4; ++j) o[db][j] *= fs;
        mrow = pm;
      }
      float p[16];
#pragma unroll
      for (int j = 0; j < 16; ++j)
        p[j] = (sv[j] > -1e29f) ? __builtin_amdgcn_exp2f(sv[j] - mrow) : 0.0f;
      float ps = 0.f;
#pragma unroll
      for (int j = 0; j < 16; ++j) ps += p[j];
      ps += __shfl_xor(ps, 16);
      ps += __shfl_xor(ps, 32);
      lrow += ps;
#pragma unroll
      for (int s = 0; s < 4; ++s) {
        uint2 pw = { pk2(p[s * 4], p[s * 4 + 1]), pk2(p[s * 4 + 2], p[s * 4 + 3]) };
        *reinterpret_cast<uint2*>(prow + ((s * 32 + g * 8) ^ pswz)) = pw;
      }
      asm volatile("" ::: "memory");
      __builtin_amdgcn_s_setprio(1);
#pragma unroll
      for (int half = 0; half < 2; ++half) {
        bf16x8 pf = *reinterpret_cast<const bf16x8*>(prow + ((half * 64 + g * 16) ^ pswz));
#pragma unroll
        for (int db = 0; db < 8; ++db) {
          bf16x8 vf = *reinterpret_cast<const bf16x8*>(
              (char*)Vs[cur] + (db * 16 + l15) * 128 + ((((half << 2) | g) ^ (l15 & 7)) << 4));
          o[db] = __builtin_amdgcn_mfma_f32_16x16x32_bf16(vf, pf, o[db], 0, 0, 0);
        }
      }
      __builtin_amdgcn_s_setprio(0);
    }
    __syncthreads();
    cur ^= 1;
  }

  const float invL = 1.0f / lrow;
#pragma unroll
  for (int db = 0; db < 8; ++db) {
    int d0 = db * 16 + g * 4;
    uint2 gw = *reinterpret_cast<const uint2*>(qg + (size_t)qrow * 4096 + h * 256 + 128 + d0);
    u16 gu[4] = { (u16)(gw.x & 0xffff), (u16)(gw.x >> 16),
                  (u16)(gw.y & 0xffff), (u16)(gw.y >> 16) };
    u16 ou[4];
#pragma unroll
    for (int j = 0; j < 4; ++j) {
      float gate = b2f(gu[j]);
      float sig = 1.0f / (1.0f + __expf(-gate));
      ou[j] = f2b(o[db][j] * invL * sig);
    }
    *reinterpret_cast<uint2*>(outg + (size_t)qrow * 2048 + h * 128 + d0) =
        *reinterpret_cast<uint2*>(ou);
  }
}

extern "C" void kernel_launch(void* const* d_in, const int* in_sizes, int n_in,
                              void* d_out, int out_size, void* d_ws, size_t ws_size,
                              hipStream_t stream) {
  const float* x    = (const float*)d_in[0];
  const float* cosb = (const float*)d_in[1];
  const float* sinb = (const float*)d_in[2];
  const float* Wq   = (const float*)d_in[3];
  const float* Wk   = (const float*)d_in[4];
  const float* Wv   = (const float*)d_in[5];
  const float* Wo   = (const float*)d_in[6];
  const float* qnw  = (const float*)d_in[7];
  const float* knw  = (const float*)d_in[8];
  const int*   cu   = (const int*)d_in[9];
  const int n_seq = in_sizes[9] - 1;

  const int hidden = 2048, H = 16, KVH = 4, D = 128;
  const int total = in_sizes[0] / hidden;  // 4096
  const int NQ = H * D * 2;                // 4096
  const int NKV = KVH * D;                 // 512

  char* ws = (char*)d_ws;
  size_t off = 0;
  auto alloc = [&](size_t elems) {
    u16* p = (u16*)(ws + off);
    off += elems * 2;
    off = (off + 255) & ~(size_t)255;
    return p;
  };
  u16* xb   = alloc((size_t)total * hidden);
  u16* Wqb  = alloc((size_t)NQ * hidden);    // Wqb|Wkb|Wvb contiguous => merged B (5120 x 2048)
  u16* Wkb  = alloc((size_t)NKV * hidden);
  u16* Wvb  = alloc((size_t)NKV * hidden);
  u16* Wob  = alloc((size_t)hidden * (H * D));
  u16* qgb  = alloc((size_t)total * NQ);
  u16* kbuf = alloc((size_t)total * NKV);
  u16* vbuf = alloc((size_t)total * NKV);
  u16* vtb  = alloc((size_t)total * NKV);
  u16* attg = Wqb;  // alias: Wqb dead after the qkv GEMM

  // fused bf16 conversion (1 launch)
  F2BArgs fa;
  fa.s0 = x;  fa.s1 = Wq;  fa.s2 = Wk;  fa.s3 = Wv;  fa.s4 = Wo;
  fa.d0 = xb; fa.d1 = Wqb; fa.d2 = Wkb; fa.d3 = Wvb; fa.d4 = Wob;
  int g0 = total * hidden / 4, g1 = NQ * hidden / 4, g2 = NKV * hidden / 4;
  int g3 = NKV * hidden / 4, g4 = hidden * H * D / 4;
  fa.e0 = g0; fa.e1 = fa.e0 + g1; fa.e2 = fa.e1 + g2; fa.e3 = fa.e2 + g3; fa.e4 = fa.e3 + g4;
  k_f2b5<<<2048, 256, 0, stream>>>(fa);

  // fused qkv projection: BM=256 BN=160 WN=2 => 32x16 = 512 blocks = 2 blocks/CU, 1 round
  const int Nqkv = NQ + 2 * NKV;  // 5120
  k_gemmU<256, 160, 2, 2, 1><<<dim3(Nqkv / 160, total / 256), 512, 0, stream>>>(
      xb, Wqb, qgb, kbuf, vbuf, total, Nqkv, hidden, NQ, NKV);
  k_transpose<<<dim3(total / 32, NKV / 32), 256, 0, stream>>>(vbuf, vtb, total, NKV);
  const float qscale = 0.08838834764831845f * 1.4426950408889634f;  // 1/sqrt(D) * log2(e)
  k_normrope2<<<total * (H + KVH) / 4, 256, 0, stream>>>(qgb, kbuf, cosb, sinb, qnw, knw,
                                                         total, qscale);
  k_attn<<<dim3(total / 128, H), 512, 0, stream>>>(qgb, kbuf, vtb, attg, cu, n_seq, total);
  // out = attg @ Wo^T: round-7 proven soft-phase BK=64, BN=128 => 256 blocks = 1 round
  k_gemmS<128, 4, 2, 0><<<dim3(hidden / 128, total / 256), 512, 0, stream>>>(
      attg, Wob, (float*)d_out, nullptr, nullptr, total, hidden, H * D, 0, 0);
}

// Round 18
// 223.972 us; speedup vs baseline: 1.5952x; 1.0072x over previous
//
#include <hip/hip_runtime.h>
#include <stdint.h>

typedef unsigned short u16;
typedef __bf16 bf16_t;
typedef bf16_t bf16x8 __attribute__((ext_vector_type(8)));
typedef float f32x4 __attribute__((ext_vector_type(4)));

__device__ __forceinline__ float b2f(u16 u) {
  union { unsigned int i; float f; } v; v.i = ((unsigned int)u) << 16; return v.f;
}
__device__ __forceinline__ u16 f2b(float f) {
  union { float f; unsigned int i; } v; v.f = f;
  unsigned int r = v.i + 0x7fffu + ((v.i >> 16) & 1u);  // RNE
  return (u16)(r >> 16);
}
__device__ __forceinline__ unsigned int pk2(float a, float b) {
  return (unsigned int)f2b(a) | ((unsigned int)f2b(b) << 16);
}
__device__ __forceinline__ void async16(const void* g, void* lds) {
  __builtin_amdgcn_global_load_lds((const __attribute__((address_space(1))) void*)g,
                                   (__attribute__((address_space(3))) void*)lds,
                                   16, 0, 0);
}

// ---------------- fused fp32 -> bf16 conversion (5 buffers, 1 launch) ----------------
struct F2BArgs {
  const float *s0, *s1, *s2, *s3, *s4;
  u16 *d0, *d1, *d2, *d3, *d4;
  int e0, e1, e2, e3, e4;  // prefix ends, in 4-element groups
};
__global__ __launch_bounds__(256) void k_f2b5(F2BArgs a) {
  int g = blockIdx.x * 256 + threadIdx.x;
  const int stride = gridDim.x * 256;
  for (; g < a.e4; g += stride) {
    const float* s; u16* d; int off;
    if (g < a.e0)      { s = a.s0; d = a.d0; off = g; }
    else if (g < a.e1) { s = a.s1; d = a.d1; off = g - a.e0; }
    else if (g < a.e2) { s = a.s2; d = a.d2; off = g - a.e1; }
    else if (g < a.e3) { s = a.s3; d = a.d3; off = g - a.e2; }
    else               { s = a.s4; d = a.d4; off = g - a.e3; }
    float4 v = *reinterpret_cast<const float4*>(s + (size_t)off * 4);
    u16 o[4] = { f2b(v.x), f2b(v.y), f2b(v.z), f2b(v.w) };
    *reinterpret_cast<uint2*>(d + (size_t)off * 4) = *reinterpret_cast<uint2*>(o);
  }
}

// ---------------- BK=32 2-blocks/CU soft-phase GEMM (qkv): C = A(MxK) * B(NxK)^T ----------
// A double-buffered, B triple-slot staged 2 K-tiles ahead; one counted vmcnt(BSTG) +
// barrier per K-tile. 63 KB LDS = 2 blocks/CU. Swizzle: chunk XOR (row>>1)&3.
// XCD mapping: 8x8 tile square per XCD (L2 working set 13 MB vs 22 MB row-strip).
template<int BM, int BN, int WN, int BSTG, int SPLIT>
__global__ __launch_bounds__(512, 4) void k_gemmU(const u16* __restrict__ A,
                                                  const u16* __restrict__ B,
                                                  void* __restrict__ C0,
                                                  u16* __restrict__ Ck, u16* __restrict__ Cv,
                                                  int M, int N, int K, int nqc, int nkc) {
  constexpr int ALD = BM / 128;                      // A chunks per thread
  constexpr int NF = BN / WN / 16;                   // B frags per wave
  __shared__ __align__(16) u16 SA[2][BM * 32];       // double buffer
  __shared__ __align__(16) u16 SB[3][BN * 32];       // triple slot
  __shared__ __align__(16) u16 dscr[512];            // pad sink
  const int tid = threadIdx.x, lane = tid & 63, w = tid >> 6;
  const int wm = w / WN, wn = w % WN;
  const int g = lane >> 4, l15 = lane & 15;

  int ntx = gridDim.x, nty = gridDim.y;
  int id = blockIdx.y * ntx + blockIdx.x;
  int nwg = ntx * nty;
  if ((ntx & 7) == 0 && (nty & 7) == 0 && ((ntx >> 3) * (nty >> 3)) == 8) {
    // square 8x8 chunk per XCD (bijective): xcd -> (chunk row, chunk col)
    int ncc = ntx >> 3;
    int xcd = id & 7, w8 = id >> 3;
    int mrow = (xcd / ncc) * 8 + (w8 >> 3);
    int ncol = (xcd % ncc) * 8 + (w8 & 7);
    id = mrow * ntx + ncol;
  } else if ((nwg & 7) == 0) {
    int q = nwg >> 3; id = (id & 7) * q + (id >> 3);
  }
  const int m0 = (id / ntx) * BM, n0 = (id % ntx) * BN;
  const int NT = K >> 5;
  const int rsw = (l15 >> 1) & 3;                    // read-side row-XOR key

  auto stageA = [&](int buf, int kb) {
#pragma unroll
    for (int j = 0; j < ALD; ++j) {
      int c = j * 512 + tid;
      int r = c >> 2, cp = c & 3;
      async16(A + (size_t)(m0 + r) * K + kb + ((cp ^ ((r >> 1) & 3)) << 3),
              (char*)SA[buf] + c * 16);
    }
  };
  auto stageB = [&](int slot, int kb) {
#pragma unroll
    for (int j = 0; j < BSTG; ++j) {
      int c = j * 512 + tid;
      if (c < BN * 4) {
        int r = c >> 2, cp = c & 3;
        async16(B + (size_t)(n0 + r) * K + kb + ((cp ^ ((r >> 1) & 3)) << 3),
                (char*)SB[slot] + c * 16);
      } else {
        async16(B, (char*)dscr + lane * 16);         // uniform vmcnt pad (wave-uniform)
      }
    }
  };

  // prologue: A(0), B(0), B(1); leave B(1)'s loads in flight
  stageA(0, 0);
  stageB(0, 0);
  if (NT > 1) stageB(1, 32);
  if (NT > 1) asm volatile("s_waitcnt vmcnt(%0)" :: "n"(BSTG) : "memory");
  else        asm volatile("s_waitcnt vmcnt(0)" ::: "memory");
  __builtin_amdgcn_s_barrier();
  asm volatile("" ::: "memory");

  f32x4 acc[4][NF] = {};
  int c3 = 0;                                        // kt % 3
  for (int kt = 0; kt < NT; ++kt) {
    const int cur = kt & 1;
    const char* bb = (const char*)SB[c3];
    bf16x8 bfr[NF];
#pragma unroll
    for (int n = 0; n < NF; ++n) {
      int row = wn * (BN / WN) + n * 16 + l15;
      bfr[n] = *(const bf16x8*)(bb + (size_t)row * 64 + ((g ^ rsw) << 4));
    }
    if (kt + 1 < NT) stageA(cur ^ 1, (kt + 1) * 32);
    const char* ab = (const char*)SA[cur];
#pragma unroll
    for (int m = 0; m < 4; ++m) {
      int row = wm * 64 + m * 16 + l15;
      bf16x8 af = *(const bf16x8*)(ab + (size_t)row * 64 + ((g ^ rsw) << 4));
      __builtin_amdgcn_s_setprio(1);
#pragma unroll
      for (int n = 0; n < NF; ++n)
        acc[m][n] = __builtin_amdgcn_mfma_f32_16x16x32_bf16(af, bfr[n], acc[m][n], 0, 0, 0);
      __builtin_amdgcn_s_setprio(0);
    }
    int b2 = c3 + 2; if (b2 >= 3) b2 -= 3;
    if (kt + 2 < NT) stageB(b2, (kt + 2) * 32);
    asm volatile("" ::: "memory");
    if (kt + 2 < NT)      asm volatile("s_waitcnt vmcnt(%0)" :: "n"(BSTG) : "memory");
    else if (kt + 1 < NT) asm volatile("s_waitcnt vmcnt(0)" ::: "memory");
    asm volatile("" ::: "memory");
    __builtin_amdgcn_s_barrier();
    asm volatile("" ::: "memory");
    c3 = (c3 == 2) ? 0 : c3 + 1;
  }

  const int er = g * 4;
  if constexpr (SPLIT == 0) {
    float* C = (float*)C0;
#pragma unroll
    for (int m = 0; m < 4; ++m)
#pragma unroll
      for (int n = 0; n < NF; ++n)
#pragma unroll
        for (int jj = 0; jj < 4; ++jj)
          C[(size_t)(m0 + wm * 64 + m * 16 + er + jj) * N + n0 + wn * (BN / WN) + n * 16 + l15] =
              acc[m][n][jj];
  } else {
#pragma unroll
    for (int n = 0; n < NF; ++n) {
      int col0 = n0 + wn * (BN / WN) + n * 16;       // 16-col frag never straddles a region
      u16* dst; int stride, coff;
      if (col0 < nqc)            { dst = (u16*)C0; stride = nqc; coff = 0; }
      else if (col0 < nqc + nkc) { dst = Ck;       stride = nkc; coff = nqc; }
      else                       { dst = Cv;       stride = nkc; coff = nqc + nkc; }
#pragma unroll
      for (int m = 0; m < 4; ++m)
#pragma unroll
        for (int jj = 0; jj < 4; ++jj)
          dst[(size_t)(m0 + wm * 64 + m * 16 + er + jj) * stride + (col0 - coff) + l15] =
              f2b(acc[m][n][jj]);
    }
  }
}

// ---------------- soft-phase 8-wave GEMM, BK=64 (round-7 proven; out-proj) ----------------
template<int BN, int NF, int BSTG, int SPLIT>
__global__ __launch_bounds__(512, 2) void k_gemmS(const u16* __restrict__ A,
                                                  const u16* __restrict__ B,
                                                  void* __restrict__ C0,
                                                  u16* __restrict__ Ck, u16* __restrict__ Cv,
                                                  int M, int N, int K, int nqc, int nkc) {
  __shared__ __align__(16) u16 SA[2][2][128 * 64];   // [buf][half] 64 KB
  __shared__ __align__(16) u16 SB[3][BN * 64];       // 3-buffer rotation
  __shared__ __align__(16) u16 dscr[512];
  const int tid = threadIdx.x, lane = tid & 63, w = tid >> 6;
  const int wm = w >> 1, wn = w & 1;                 // 4M x 2N wave grid
  const int g = lane >> 4, l15 = lane & 15;

  int ntx = gridDim.x;
  int id = blockIdx.y * ntx + blockIdx.x;
  int nwg = ntx * gridDim.y;
  if ((nwg & 7) == 0) { int q = nwg >> 3; id = (id & 7) * q + (id >> 3); }
  const int m0 = (id / ntx) * 256, n0 = (id % ntx) * BN;
  const int NT = K >> 6;

  auto stageA = [&](int buf, int half, int kb) {
#pragma unroll
    for (int j = 0; j < 2; ++j) {
      int c = j * 512 + tid;
      int r = c >> 3, cp = c & 7;
      async16(A + (size_t)(m0 + half * 128 + r) * K + kb + ((cp ^ (r & 7)) << 3),
              (char*)SA[buf][half] + c * 16);
    }
  };
  auto stageB = [&](int buf, int kb) {
#pragma unroll
    for (int j = 0; j < BSTG; ++j) {
      int c = j * 512 + tid;
      if (c < BN * 8) {
        int r = c >> 3, cp = c & 7;
        async16(B + (size_t)(n0 + r) * K + kb + ((cp ^ (r & 7)) << 3),
                (char*)SB[buf] + c * 16);
      } else {
        async16(B, (char*)dscr + lane * 16);
      }
    }
  };

  stageA(0, 0, 0); stageA(0, 1, 0);
  stageB(0, 0);
  if (NT > 1) stageB(1, 64);
  if constexpr (BSTG == 3) asm volatile("s_waitcnt vmcnt(3)" ::: "memory");
  else                     asm volatile("s_waitcnt vmcnt(2)" ::: "memory");
  __builtin_amdgcn_s_barrier();
  asm volatile("" ::: "memory");

  f32x4 acc[4][NF] = {};
  int c3 = 0;
  for (int kt = 0; kt < NT; ++kt) {
    const int cur = kt & 1;
    const char* bb = (const char*)SB[c3];
    bf16x8 bfr[NF][2];
#pragma unroll
    for (int n = 0; n < NF; ++n)
#pragma unroll
      for (int ks = 0; ks < 2; ++ks)
        bfr[n][ks] = *(const bf16x8*)(bb + (size_t)(wn * (BN / 2) + n * 16 + l15) * 128 +
                                      ((((ks << 2) | g) ^ (l15 & 7)) << 4));
    if (kt + 1 < NT) { stageA(cur ^ 1, 0, (kt + 1) * 64); stageA(cur ^ 1, 1, (kt + 1) * 64); }
    const char* ab = (const char*)SA[cur][wm >> 1];
    const int rb = (wm & 1) * 64;
#pragma unroll
    for (int m = 0; m < 4; ++m) {
      bf16x8 af[2];
#pragma unroll
      for (int ks = 0; ks < 2; ++ks)
        af[ks] = *(const bf16x8*)(ab + (size_t)(rb + m * 16 + l15) * 128 +
                                  ((((ks << 2) | g) ^ (l15 & 7)) << 4));
      __builtin_amdgcn_s_setprio(1);
#pragma unroll
      for (int n = 0; n < NF; ++n)
#pragma unroll
        for (int ks = 0; ks < 2; ++ks)
          acc[m][n] = __builtin_amdgcn_mfma_f32_16x16x32_bf16(af[ks], bfr[n][ks], acc[m][n],
                                                              0, 0, 0);
      __builtin_amdgcn_s_setprio(0);
    }
    int b2 = c3 + 2; if (b2 >= 3) b2 -= 3;
    if (kt + 2 < NT) stageB(b2, (kt + 2) * 64);
    asm volatile("" ::: "memory");
    if (kt + 2 < NT) {
      if constexpr (BSTG == 3) asm volatile("s_waitcnt vmcnt(3)" ::: "memory");
      else                     asm volatile("s_waitcnt vmcnt(2)" ::: "memory");
    } else {
      asm volatile("s_waitcnt vmcnt(0)" ::: "memory");
    }
    __builtin_amdgcn_s_barrier();
    asm volatile("" ::: "memory");
    c3 = (c3 == 2) ? 0 : c3 + 1;
  }

  const int er = g * 4;
  if constexpr (SPLIT == 0) {
    float* C = (float*)C0;
#pragma unroll
    for (int m = 0; m < 4; ++m)
#pragma unroll
      for (int n = 0; n < NF; ++n)
#pragma unroll
        for (int jj = 0; jj < 4; ++jj)
          C[(size_t)(m0 + wm * 64 + m * 16 + er + jj) * N + n0 + wn * (BN / 2) + n * 16 + l15] =
              acc[m][n][jj];
  } else {
#pragma unroll
    for (int n = 0; n < NF; ++n) {
      int col0 = n0 + wn * (BN / 2) + n * 16;
      u16* dst; int stride, coff;
      if (col0 < nqc)            { dst = (u16*)C0; stride = nqc; coff = 0; }
      else if (col0 < nqc + nkc) { dst = Ck;       stride = nkc; coff = nqc; }
      else                       { dst = Cv;       stride = nkc; coff = nqc + nkc; }
#pragma unroll
      for (int m = 0; m < 4; ++m)
#pragma unroll
        for (int jj = 0; jj < 4; ++jj)
          dst[(size_t)(m0 + wm * 64 + m * 16 + er + jj) * stride + (col0 - coff) + l15] =
              f2b(acc[m][n][jj]);
    }
  }
}

// ---------------- RMSNorm(offset) + RoPE for K only (Q fused into attention) --------------
__global__ __launch_bounds__(256) void k_normropeK(u16* __restrict__ kbuf,
                                                   const float* __restrict__ cosb,
                                                   const float* __restrict__ sinb,
                                                   const float* __restrict__ kw,
                                                   int total) {
  int wid = blockIdx.x * 4 + (threadIdx.x >> 6);
  int lane = threadIdx.x & 63;
  int t = wid >> 2, h = wid & 3;
  if (t >= total) return;
  u16* base = kbuf + (size_t)t * 512 + h * 128;
  float a = b2f(base[lane]), b = b2f(base[lane + 64]);
  float ss = a * a + b * b;
#pragma unroll
  for (int m = 32; m >= 1; m >>= 1) ss += __shfl_xor(ss, m, 64);
  float r = rsqrtf(ss * (1.0f / 128.0f) + 1e-6f);
  float qa = (1.0f + kw[lane]) * a * r;
  float qb = (1.0f + kw[lane + 64]) * b * r;
  const float* cr = cosb + (size_t)t * 128;
  const float* sr = sinb + (size_t)t * 128;
  base[lane] = f2b(qa * cr[lane] - qb * sr[lane]);
  base[lane + 64] = f2b(qb * cr[lane + 64] + qa * sr[lane + 64]);
}

// ---------------- transpose (rows x cols) -> (cols x rows), bf16 ----------------
__global__ __launch_bounds__(256) void k_transpose(const u16* __restrict__ src,
                                                   u16* __restrict__ dst, int rows, int cols) {
  __shared__ u16 tile[32][33];
  int bx = blockIdx.x * 32, by = blockIdx.y * 32;
  int tx = threadIdx.x & 31, ty = threadIdx.x >> 5;
#pragma unroll
  for (int i = 0; i < 4; ++i)
    tile[ty + i * 8][tx] = src[(size_t)(bx + ty + i * 8) * cols + by + tx];
  __syncthreads();
#pragma unroll
  for (int i = 0; i < 4; ++i)
    dst[(size_t)(by + ty + i * 8) * rows + bx + tx] = tile[tx][ty + i * 8];
}

// ---------------- flash attention + gate, Q-norm/RoPE fused in prologue ----------
// 8-wave block, LDS-staged K/V, 80 KB, 2 blk/CU. Lane's 32 q-elems pair d<->d+64 in-lane
// (frag cc <-> cc^2), so RMSNorm+RoPE is 2 shuffles + in-register math.
__global__ __launch_bounds__(512) void k_attn(const u16* __restrict__ qg,  // total x 4096 (raw)
                                              const u16* __restrict__ kb,  // total x 512 (normed)
                                              const u16* __restrict__ vt,  // 512 x total
                                              u16* __restrict__ outg,      // total x 2048
                                              const int* __restrict__ cu, int n_seq, int total,
                                              const float* __restrict__ cosb,
                                              const float* __restrict__ sinb,
                                              const float* __restrict__ qnw, float qscale) {
  __shared__ __align__(16) u16 Ks[2][64 * 128];   // 32 KB
  __shared__ __align__(16) u16 Vs[2][128 * 64];   // 32 KB
  __shared__ __align__(16) u16 Ps[8][16][64];     // 16 KB, XOR-swizzled P bounce
  const int tid = threadIdx.x, lane = tid & 63, w = tid >> 6;  // w = 0..7
  const int h = blockIdx.y, kh = h >> 2;
  const int g = lane >> 4, l15 = lane & 15;

  int bx = blockIdx.x, qt = bx;
  int nbx = gridDim.x;
  int per = total / n_seq;
  if (per * n_seq == total && (per & 127) == 0 && nbx % n_seq == 0) {
    int tps = per >> 7;
    int seg = bx % n_seq;
    qt = seg * tps + (tps - 1 - bx / n_seq);
  }
  const int qb0 = qt * 128;

  int seg_start = 0, seg_end = total;
  for (int s = 0; s < n_seq; ++s) {
    int a = cu[s], b = cu[s + 1];
    if (qb0 >= a && qb0 < b) { seg_start = a; seg_end = b; }
  }
  const int qr0 = qb0 + w * 16;
  const int qrow = qr0 + l15;

  // ---- fused Q RMSNorm + RoPE + qscale (in registers) ----
  bf16x8 qraw[4];
#pragma unroll
  for (int cc = 0; cc < 4; ++cc)
    qraw[cc] = *reinterpret_cast<const bf16x8*>(qg + (size_t)qrow * 4096 + h * 256 + cc * 32 + g * 8);
  float ss = 0.f;
#pragma unroll
  for (int cc = 0; cc < 4; ++cc) {
    const u16* pu = (const u16*)&qraw[cc];
#pragma unroll
    for (int e = 0; e < 8; ++e) { float v = b2f(pu[e]); ss += v * v; }
  }
  ss += __shfl_xor(ss, 16);
  ss += __shfl_xor(ss, 32);
  const float rr = rsqrtf(ss * (1.0f / 128.0f) + 1e-6f);
  bf16x8 qf[4];
#pragma unroll
  for (int lo = 0; lo < 2; ++lo) {        // rope pair: frag lo (d<64) <-> frag lo+2 (d>=64)
    const u16* pa = (const u16*)&qraw[lo];
    const u16* pb = (const u16*)&qraw[lo + 2];
    const int da = lo * 32 + g * 8;       // d of pa[0] (in [0,64))
    const int db_ = da + 64;
    float qa[8], qb[8];
#pragma unroll
    for (int e = 0; e < 8; ++e) {
      qa[e] = (1.0f + qnw[da + e]) * b2f(pa[e]) * rr;
      qb[e] = (1.0f + qnw[db_ + e]) * b2f(pb[e]) * rr;
    }
    const float* ca = cosb + (size_t)qrow * 128 + da;
    const float* sa = sinb + (size_t)qrow * 128 + da;
    const float* cb = cosb + (size_t)qrow * 128 + db_;
    const float* sb = sinb + (size_t)qrow * 128 + db_;
    u16 oa[8], ob[8];
#pragma unroll
    for (int e = 0; e < 8; ++e) {
      oa[e] = f2b((qa[e] * ca[e] - qb[e] * sa[e]) * qscale);
      ob[e] = f2b((qb[e] * cb[e] + qa[e] * sb[e]) * qscale);
    }
    qf[lo] = *reinterpret_cast<bf16x8*>(oa);
    qf[lo + 2] = *reinterpret_cast<bf16x8*>(ob);
  }

  int blk_end = qb0 + 128; if (blk_end > seg_end) blk_end = seg_end;
  const int NT = (blk_end - seg_start + 63) >> 6;
  int my_end = qr0 + 16; if (my_end > seg_end) my_end = seg_end;
  const int myNT = (my_end - seg_start + 63) >> 6;

  f32x4 o[8] = {};
  float mrow = -1e30f, lrow = 0.f;
  char* prow = (char*)&Ps[w][l15][0];               // 128 B row stride
  const int pswz = (l15 & 7) << 4;

  {
    const int kv0 = seg_start;
#pragma unroll
    for (int i = 0; i < 2; ++i) {
      int c = i * 512 + tid;
      int r = c >> 4, k16 = c & 15;
      async16(kb + (size_t)(kv0 + r) * 512 + kh * 128 + ((k16 ^ (r & 7)) << 3),
              (char*)Ks[0] + c * 16);
      int rv = c >> 3, c8 = c & 7;
      async16(vt + (size_t)(kh * 128 + rv) * total + kv0 + ((c8 ^ (rv & 7)) << 3),
              (char*)Vs[0] + c * 16);
    }
  }
  __syncthreads();

  int cur = 0;
  for (int t = 0; t < NT; ++t) {
    if (t + 1 < NT) {
      const int kv0 = seg_start + (t + 1) * 64;
#pragma unroll
      for (int i = 0; i < 2; ++i) {
        int c = i * 512 + tid;
        int r = c >> 4, k16 = c & 15;
        async16(kb + (size_t)(kv0 + r) * 512 + kh * 128 + ((k16 ^ (r & 7)) << 3),
                (char*)Ks[cur ^ 1] + c * 16);
        int rv = c >> 3, c8 = c & 7;
        async16(vt + (size_t)(kh * 128 + rv) * total + kv0 + ((c8 ^ (rv & 7)) << 3),
                (char*)Vs[cur ^ 1] + c * 16);
      }
    }
    if (t < myNT) {
      const int kv0 = seg_start + t * 64;
      f32x4 sa[4] = {};
      __builtin_amdgcn_s_setprio(1);
#pragma unroll
      for (int cc = 0; cc < 4; ++cc)
#pragma unroll
        for (int s = 0; s < 4; ++s) {
          bf16x8 kf = *reinterpret_cast<const bf16x8*>(
              (char*)Ks[cur] + (s * 16 + l15) * 256 + ((((cc << 2) | g) ^ (l15 & 7)) << 4));
          sa[s] = __builtin_amdgcn_mfma_f32_16x16x32_bf16(kf, qf[cc], sa[s], 0, 0, 0);
        }
      __builtin_amdgcn_s_setprio(0);
      float sv[16];
#pragma unroll
      for (int s = 0; s < 4; ++s)
#pragma unroll
        for (int j = 0; j < 4; ++j)
          sv[s * 4 + j] = (kv0 + s * 16 + g * 4 + j > qrow) ? -1e30f : sa[s][j];
      float pm = sv[0];
#pragma unroll
      for (int j = 1; j < 16; ++j) pm = fmaxf(pm, sv[j]);
      pm = fmaxf(pm, __shfl_xor(pm, 16));
      pm = fmaxf(pm, __shfl_xor(pm, 32));
      if (pm > mrow + 11.5f) {
        float fs = __builtin_amdgcn_exp2f(mrow - pm);
        lrow *= fs;
#pragma unroll
        for (int db = 0; db < 8; ++db)
#pragma unroll
          for (int j = 0; j < 4; ++j) o[db][j] *= fs;
        mrow = pm;
      }
      float p[16];
#pragma unroll
      for (int j = 0; j < 16; ++j)
        p[j] = (sv[j] > -1e29f) ? __builtin_amdgcn_exp2f(sv[j] - mrow) : 0.0f;
      float ps = 0.f;
#pragma unroll
      for (int j = 0; j < 16; ++j) ps += p[j];
      ps += __shfl_xor(ps, 16);
      ps += __shfl_xor(ps, 32);
      lrow += ps;
#pragma unroll
      for (int s = 0; s < 4; ++s) {
        uint2 pw = { pk2(p[s * 4], p[s * 4 + 1]), pk2(p[s * 4 + 2], p[s * 4 + 3]) };
        *reinterpret_cast<uint2*>(prow + ((s * 32 + g * 8) ^ pswz)) = pw;
      }
      asm volatile("" ::: "memory");
      __builtin_amdgcn_s_setprio(1);
#pragma unroll
      for (int half = 0; half < 2; ++half) {
        bf16x8 pf = *reinterpret_cast<const bf16x8*>(prow + ((half * 64 + g * 16) ^ pswz));
#pragma unroll
        for (int db = 0; db < 8; ++db) {
          bf16x8 vf = *reinterpret_cast<const bf16x8*>(
              (char*)Vs[cur] + (db * 16 + l15) * 128 + ((((half << 2) | g) ^ (l15 & 7)) << 4));
          o[db] = __builtin_amdgcn_mfma_f32_16x16x32_bf16(vf, pf, o[db], 0, 0, 0);
        }
      }
      __builtin_amdgcn_s_setprio(0);
    }
    __syncthreads();
    cur ^= 1;
  }

  const float invL = 1.0f / lrow;
#pragma unroll
  for (int db = 0; db < 8; ++db) {
    int d0 = db * 16 + g * 4;
    uint2 gw = *reinterpret_cast<const uint2*>(qg + (size_t)qrow * 4096 + h * 256 + 128 + d0);
    u16 gu[4] = { (u16)(gw.x & 0xffff), (u16)(gw.x >> 16),
                  (u16)(gw.y & 0xffff), (u16)(gw.y >> 16) };
    u16 ou[4];
#pragma unroll
    for (int j = 0; j < 4; ++j) {
      float gate = b2f(gu[j]);
      float sig = 1.0f / (1.0f + __expf(-gate));
      ou[j] = f2b(o[db][j] * invL * sig);
    }
    *reinterpret_cast<uint2*>(outg + (size_t)qrow * 2048 + h * 128 + d0) =
        *reinterpret_cast<uint2*>(ou);
  }
}

extern "C" void kernel_launch(void* const* d_in, const int* in_sizes, int n_in,
                              void* d_out, int out_size, void* d_ws, size_t ws_size,
                              hipStream_t stream) {
  const float* x    = (const float*)d_in[0];
  const float* cosb = (const float*)d_in[1];
  const float* sinb = (const float*)d_in[2];
  const float* Wq   = (const float*)d_in[3];
  const float* Wk   = (const float*)d_in[4];
  const float* Wv   = (const float*)d_in[5];
  const float* Wo   = (const float*)d_in[6];
  const float* qnw  = (const float*)d_in[7];
  const float* knw  = (const float*)d_in[8];
  const int*   cu   = (const int*)d_in[9];
  const int n_seq = in_sizes[9] - 1;

  const int hidden = 2048, H = 16, KVH = 4, D = 128;
  const int total = in_sizes[0] / hidden;  // 4096
  const int NQ = H * D * 2;                // 4096
  const int NKV = KVH * D;                 // 512

  char* ws = (char*)d_ws;
  size_t off = 0;
  auto alloc = [&](size_t elems) {
    u16* p = (u16*)(ws + off);
    off += elems * 2;
    off = (off + 255) & ~(size_t)255;
    return p;
  };
  u16* xb   = alloc((size_t)total * hidden);
  u16* Wqb  = alloc((size_t)NQ * hidden);    // Wqb|Wkb|Wvb contiguous => merged B (5120 x 2048)
  u16* Wkb  = alloc((size_t)NKV * hidden);
  u16* Wvb  = alloc((size_t)NKV * hidden);
  u16* Wob  = alloc((size_t)hidden * (H * D));
  u16* qgb  = alloc((size_t)total * NQ);
  u16* kbuf = alloc((size_t)total * NKV);
  u16* vbuf = alloc((size_t)total * NKV);
  u16* vtb  = alloc((size_t)total * NKV);
  u16* attg = Wqb;  // alias: Wqb dead after the qkv GEMM

  // fused bf16 conversion (1 launch)
  F2BArgs fa;
  fa.s0 = x;  fa.s1 = Wq;  fa.s2 = Wk;  fa.s3 = Wv;  fa.s4 = Wo;
  fa.d0 = xb; fa.d1 = Wqb; fa.d2 = Wkb; fa.d3 = Wvb; fa.d4 = Wob;
  int g0 = total * hidden / 4, g1 = NQ * hidden / 4, g2 = NKV * hidden / 4;
  int g3 = NKV * hidden / 4, g4 = hidden * H * D / 4;
  fa.e0 = g0; fa.e1 = fa.e0 + g1; fa.e2 = fa.e1 + g2; fa.e3 = fa.e2 + g3; fa.e4 = fa.e3 + g4;
  k_f2b5<<<2048, 256, 0, stream>>>(fa);

  // fused qkv projection: BM=256 BN=160 WN=2 => 32x16 = 512 blocks = 2 blocks/CU, 1 round
  const int Nqkv = NQ + 2 * NKV;  // 5120
  k_gemmU<256, 160, 2, 2, 1><<<dim3(Nqkv / 160, total / 256), 512, 0, stream>>>(
      xb, Wqb, qgb, kbuf, vbuf, total, Nqkv, hidden, NQ, NKV);
  k_transpose<<<dim3(total / 32, NKV / 32), 256, 0, stream>>>(vbuf, vtb, total, NKV);
  // K norm+rope only (Q fused into attention)
  k_normropeK<<<total, 256, 0, stream>>>(kbuf, cosb, sinb, knw, total);
  const float qscale = 0.08838834764831845f * 1.4426950408889634f;  // 1/sqrt(D) * log2(e)
  k_attn<<<dim3(total / 128, H), 512, 0, stream>>>(qgb, kbuf, vtb, attg, cu, n_seq, total,
                                                   cosb, sinb, qnw, qscale);
  // out = attg @ Wo^T: round-7 proven soft-phase BK=64, BN=128 => 256 blocks = 1 round
  k_gemmS<128, 4, 2, 0><<<dim3(hidden / 128, total / 256), 512, 0, stream>>>(
      attg, Wob, (float*)d_out, nullptr, nullptr, total, hidden, H * D, 0, 0);
}